// Round 4
// baseline (610.808 us; speedup 1.0000x reference)
//
#include <hip/hip_runtime.h>
#include <hip/hip_bf16.h>
#include <math.h>

#define NN_NODES 2048
#define NE 65536
#define H1C 32
#define H2C 20
#define AW_STRIDE 4194304ull  // N*N
#define BUCKET 128            // fixed-stride CSR bucket (deg ~ Binom(65536,1/2048), 128 = 17 sigma)

// ---------------- GEMM1 + edge scatter (independent work, one dispatch) ----------------
// blocks 0..511: h_tmp[2048,32] = X[2048,2048] @ W1[2048,32], split-K via atomics
// blocks 512..767: scatter edges into fixed-stride bucket CSR; cnt doubles as degree
__global__ __launch_bounds__(256) void k_g1scat(const float* __restrict__ X,
                                                const float* __restrict__ W1,
                                                const int* __restrict__ ei,
                                                float* __restrict__ h_tmp,
                                                int* __restrict__ cnt,
                                                int* __restrict__ csr_src) {
    __shared__ float Xs[32][33];
    __shared__ __align__(16) float Ws[32][32];
    int b = blockIdx.x;
    int t = threadIdx.x;
    if (b >= 512) {
        int e = (b - 512) * 256 + t;
        int s = ei[e], d = ei[NE + e];
        int pos = atomicAdd(&cnt[d], 1);
        if (pos < BUCKET) csr_src[d * BUCKET + pos] = s;
        return;
    }
    int rg = b >> 3, kc = b & 7;
    int r0 = rg * 32;
    int r = t >> 3, c4 = (t & 7) * 4;
    float4 acc = {0.f, 0.f, 0.f, 0.f};
    for (int kt = 0; kt < 8; ++kt) {
        int k0 = kc * 256 + kt * 32;
#pragma unroll
        for (int i = 0; i < 4; ++i) {
            int id = t + i * 256;
            int rr = id >> 5, kk = id & 31;
            Xs[rr][kk] = X[(size_t)(r0 + rr) * 2048 + k0 + kk];
            Ws[rr][kk] = W1[(size_t)(k0 + rr) * 32 + kk];
        }
        __syncthreads();
#pragma unroll
        for (int kk = 0; kk < 32; ++kk) {
            float a = Xs[r][kk];
            float4 bb = *(const float4*)&Ws[kk][c4];
            acc.x += a * bb.x; acc.y += a * bb.y; acc.z += a * bb.z; acc.w += a * bb.w;
        }
        __syncthreads();
    }
    float* dst = &h_tmp[(size_t)(r0 + r) * 32 + c4];
    atomicAdd(dst + 0, acc.x);
    atomicAdd(dst + 1, acc.y);
    atomicAdd(dst + 2, acc.z);
    atomicAdd(dst + 3, acc.w);
}

// ---------------- agg1 fused with GEMM2 epilogue ----------------
// norm recomputed per edge from cnt (== degree): rsqrtf(cnt[src]+1)*rsqrtf(cnt[n]+1)
// h1row = relu(b1 + self + sum_edges h[src]*norm) in LDS; h2t[n][:] = h1row @ W2
__global__ __launch_bounds__(256) void k_agg1(const float* __restrict__ h,
                                              const int* __restrict__ csr_src,
                                              const int* __restrict__ cnt,
                                              const float* __restrict__ b1,
                                              const float* __restrict__ W2,
                                              float* __restrict__ h2t) {
    __shared__ float W2s[H1C * H2C];  // 640
    __shared__ float red[8][32];
    __shared__ float hrow[32];
    int n = blockIdx.x;
    int t = threadIdx.x;
    for (int i = t; i < H1C * H2C; i += 256) W2s[i] = W2[i];
    int c = t & 31, s = t >> 5;  // 8 edge slices x 32 channel lanes
    int cn = cnt[n];
    float nd = rsqrtf((float)(cn + 1));
    float acc = 0.f;
    int e0 = n * BUCKET;
    for (int e = s; e < cn; e += 8) {
        int src = csr_src[e0 + e];
        float nrm = rsqrtf((float)(cnt[src] + 1)) * nd;
        acc += h[(size_t)src * 32 + c] * nrm;
    }
    red[s][c] = acc;
    __syncthreads();  // also covers W2s visibility
    if (t < 32) {
        float v = red[0][t];
#pragma unroll
        for (int i = 1; i < 8; ++i) v += red[i][t];
        v += h[(size_t)n * 32 + t] * nd * nd + b1[t];
        hrow[t] = fmaxf(v, 0.f);
    }
    __syncthreads();
    if (t < H2C) {
        float a = 0.f;
#pragma unroll
        for (int k = 0; k < H1C; ++k) a += hrow[k] * W2s[k * H2C + t];
        h2t[(size_t)n * H2C + t] = a;
    }
}

// ---------------- agg2 fused with x_actor accumulation ----------------
__global__ __launch_bounds__(256) void k_agg2(const float* __restrict__ h2t,
                                              const int* __restrict__ csr_src,
                                              const int* __restrict__ cnt,
                                              const float* __restrict__ b2,
                                              float* __restrict__ xa_slots) {
    __shared__ float red[8][32];
    int n = blockIdx.x;
    int t = threadIdx.x;
    int c = t & 31, s = t >> 5;
    int cn = cnt[n];
    float nd = rsqrtf((float)(cn + 1));
    float acc = 0.f;
    int e0 = n * BUCKET;
    if (c < H2C) {
        for (int e = s; e < cn; e += 8) {
            int src = csr_src[e0 + e];
            float nrm = rsqrtf((float)(cnt[src] + 1)) * nd;
            acc += h2t[(size_t)src * H2C + c] * nrm;
        }
    }
    red[s][c] = acc;
    __syncthreads();
    if (t < H2C) {
        float v = red[0][t];
#pragma unroll
        for (int i = 1; i < 8; ++i) v += red[i][t];
        v += h2t[(size_t)n * H2C + t] * nd * nd + b2[t];
        v = fmaxf(v, 0.f);
        atomicAdd(&xa_slots[(n & 31) * H2C + t], v);
    }
}

// ---------------- per-row logits + stats + global best + fused final (last block) ----------------
// Global best row via atomicMax on ~((bits(Z)<<32)|row): Z>=1 so float bits are
// order-monotone; complement lets the zero-memset be the init value.
// After publishing stats each block increments 'done'; the 2048th arrival (all
// stats + best published, device-scope atomics) runs the final phase in-place.
__global__ __launch_bounds__(256) void k_rows(const float* __restrict__ aW,
                                              const float* __restrict__ ab,
                                              const float* __restrict__ xa_slots,
                                              const float* __restrict__ cW,
                                              const float* __restrict__ cb,
                                              float* __restrict__ rowM,
                                              float* __restrict__ rowZ,
                                              int* __restrict__ rowC,
                                              float* __restrict__ rowPM,
                                              int* __restrict__ rowPC,
                                              unsigned long long* __restrict__ best,
                                              unsigned int* __restrict__ done,
                                              float* __restrict__ out) {
    __shared__ float xa[20];
    __shared__ float redf[256];
    __shared__ int redi[256];
    __shared__ int lastblk;
    int t = threadIdx.x;
    int row = blockIdx.x;
    if (t < 20) {
        float s = 0.f;
#pragma unroll
        for (int i = 0; i < 32; ++i) s += xa_slots[i * 20 + t];
        xa[t] = s * (1.0f / 2048.0f);
    }
    __syncthreads();
    size_t base = (size_t)row * 2048;
    float l[8];
#pragma unroll
    for (int u = 0; u < 2; ++u) {
        int j0 = u * 1024 + t * 4;
        float4 acc = *(const float4*)&ab[base + j0];
#pragma unroll
        for (int k = 0; k < 20; ++k) {
            float4 w = *(const float4*)&aW[(size_t)k * AW_STRIDE + base + j0];
            float sv = xa[k];
            acc.x += sv * w.x; acc.y += sv * w.y; acc.z += sv * w.z; acc.w += sv * w.w;
        }
        l[u * 4 + 0] = acc.x; l[u * 4 + 1] = acc.y;
        l[u * 4 + 2] = acc.z; l[u * 4 + 3] = acc.w;
    }
    // thread-local max/argmax (cols visited in increasing order -> strict > keeps first)
    float m = l[0];
    int mi = t * 4;
#pragma unroll
    for (int q = 1; q < 8; ++q) {
        int col = (q >> 2) * 1024 + t * 4 + (q & 3);
        if (l[q] > m) { m = l[q]; mi = col; }
    }
    redf[t] = m; redi[t] = mi;
    __syncthreads();
    for (int o = 128; o >= 1; o >>= 1) {
        if (t < o) {
            float vo = redf[t + o]; int io = redi[t + o];
            if (vo > redf[t] || (vo == redf[t] && io < redi[t])) { redf[t] = vo; redi[t] = io; }
        }
        __syncthreads();
    }
    float M = redf[0];
    int C1 = redi[0];
    __syncthreads();
    float zsum = 0.f;
#pragma unroll
    for (int q = 0; q < 8; ++q) zsum += expf(l[q] - M);
    redf[t] = zsum;
    __syncthreads();
    for (int o = 128; o >= 1; o >>= 1) {
        if (t < o) redf[t] += redf[t + o];
        __syncthreads();
    }
    float Z = redf[0];
    __syncthreads();
    // prefix (cols < C1) max/argmax over the same register-resident logits
    float pm = -INFINITY; int pj = 0x7fffffff;
#pragma unroll
    for (int q = 0; q < 8; ++q) {
        int col = (q >> 2) * 1024 + t * 4 + (q & 3);
        if (col < C1 && l[q] > pm) { pm = l[q]; pj = col; }
    }
    redf[t] = pm; redi[t] = pj;
    __syncthreads();
    for (int o = 128; o >= 1; o >>= 1) {
        if (t < o) {
            float vo = redf[t + o]; int io = redi[t + o];
            if (vo > redf[t] || (vo == redf[t] && io < redi[t])) { redf[t] = vo; redi[t] = io; }
        }
        __syncthreads();
    }
    if (t == 0) {
        rowM[row] = M; rowZ[row] = Z; rowC[row] = C1;
        rowPM[row] = redf[0]; rowPC[row] = redi[0];
        unsigned long long packed =
            ((unsigned long long)__float_as_uint(Z) << 32) | (unsigned int)row;
        atomicMax(best, ~packed);  // min Z, tie -> min row
        __threadfence();           // release: stats + best visible before done++
        unsigned int old = atomicAdd(done, 1u);
        lastblk = (old == 2047u);
    }
    __syncthreads();
    if (!lastblk) return;
    __threadfence();  // acquire side

    // ---- fused final phase (runs in exactly one block; xa already in LDS) ----
    __shared__ float sM1, sZ1;
    __shared__ int sR1, sC1, sR2, sC2;
    if (t == 0) {
        unsigned long long bb = ~(*best);
        int r1 = (int)(unsigned int)(bb & 0xffffffffULL);
        sR1 = r1;
        sZ1 = __uint_as_float((unsigned int)(bb >> 32));
        sM1 = rowM[r1];
        sC1 = rowC[r1];
    }
    __syncthreads();
    int r1 = sR1, c1 = sC1;

    // Phase B1: best full row among rows < r1
    float z = INFINITY; int zi = 0x7fffffff;
    for (int i = t; i < r1; i += 256) {
        float v = rowZ[i];
        if (v < z || (v == z && i < zi)) { z = v; zi = i; }
    }
    redf[t] = z; redi[t] = zi;
    __syncthreads();
    for (int o = 128; o >= 1; o >>= 1) {
        if (t < o) {
            float vo = redf[t + o]; int io = redi[t + o];
            if (vo < redf[t] || (vo == redf[t] && io < redi[t])) { redf[t] = vo; redi[t] = io; }
        }
        __syncthreads();
    }
    float ZP = redf[0]; int iP = redi[0];
    __syncthreads();

    if (t == 0) {
        int r2, c2;
        if (r1 == 0 && c1 == 0) {
            r2 = 0; c2 = 0;  // argmax over all -inf -> index 0
        } else {
            bool hasA = (r1 > 0), hasB = (c1 > 0);
            float pA = hasA ? 1.0f / ZP : -INFINITY;
            float pB = hasB ? expf(rowPM[r1] - sM1) / sZ1 : -INFINITY;
            if (hasB && (!hasA || pB > pA)) { r2 = r1; c2 = rowPC[r1]; }
            else                            { r2 = iP; c2 = rowC[iP]; }
        }
        sR2 = r2; sC2 = c2;
        out[0] = (float)r1; out[1] = (float)c1;
        out[2] = (float)r2; out[3] = (float)c2;
        float cr = 0.f;
#pragma unroll
        for (int k = 0; k < 20; ++k) cr += xa[k] * cW[k];
        out[8] = cr + cb[0];
    }
    __syncthreads();

    // Phase C: log_probs index the FLATTENED probs at {r1,c1,r2,c2} => row 0 of probs
    if (t < 4) {
        int a = (t == 0) ? sR1 : (t == 1) ? sC1 : (t == 2) ? sR2 : sC2;
        float acc = ab[a];
#pragma unroll
        for (int k = 0; k < 20; ++k) acc += xa[k] * aW[(size_t)k * AW_STRIDE + a];
        float lp = (acc - rowM[0]) - logf(rowZ[0]);
        out[4 + t] = -lp;
    }
}

extern "C" void kernel_launch(void* const* d_in, const int* in_sizes, int n_in,
                              void* d_out, int out_size, void* d_ws, size_t ws_size,
                              hipStream_t stream) {
    const float* x  = (const float*)d_in[0];
    const int*   ei = (const int*)d_in[1];
    const float* W1 = (const float*)d_in[2];
    const float* b1 = (const float*)d_in[3];
    const float* W2 = (const float*)d_in[4];
    const float* b2 = (const float*)d_in[5];
    const float* aW = (const float*)d_in[6];
    const float* ab = (const float*)d_in[7];
    const float* cW = (const float*)d_in[8];
    const float* cb = (const float*)d_in[9];
    float* out = (float*)d_out;

    char* p = (char*)d_ws;
    auto alloc = [&](size_t bytes) {
        void* r = (void*)p;
        p += (bytes + 255) & ~(size_t)255;
        return r;
    };
    // zero region (one memset): cnt, xa_slots, h_tmp, best, done
    int*   cnt      = (int*)alloc(2048 * 4);
    float* xa_slots = (float*)alloc(640 * 4);
    float* h_tmp    = (float*)alloc(65536 * 4);
    unsigned long long* best = (unsigned long long*)alloc(8);
    unsigned int* done = (unsigned int*)alloc(4);
    size_t zero_bytes = (size_t)(p - (char*)d_ws);
    int*   csr_src  = (int*)alloc(2048 * BUCKET * 4);
    float* h2t      = (float*)alloc(40960 * 4);
    float* rowM     = (float*)alloc(2048 * 4);
    float* rowZ     = (float*)alloc(2048 * 4);
    int*   rowC     = (int*)alloc(2048 * 4);
    float* rowPM    = (float*)alloc(2048 * 4);
    int*   rowPC    = (int*)alloc(2048 * 4);

    hipMemsetAsync(d_ws, 0, zero_bytes, stream);
    k_g1scat<<<768, 256, 0, stream>>>(x, W1, ei, h_tmp, cnt, csr_src);
    k_agg1<<<2048, 256, 0, stream>>>(h_tmp, csr_src, cnt, b1, W2, h2t);
    k_agg2<<<2048, 256, 0, stream>>>(h2t, csr_src, cnt, b2, xa_slots);
    k_rows<<<2048, 256, 0, stream>>>(aW, ab, xa_slots, cW, cb,
                                     rowM, rowZ, rowC, rowPM, rowPC, best, done, out);
}

// Round 5
// 515.258 us; speedup vs baseline: 1.1854x; 1.1854x over previous
//
#include <hip/hip_runtime.h>
#include <hip/hip_bf16.h>
#include <math.h>

#define NN_NODES 2048
#define NE 65536
#define H1C 32
#define H2C 20
#define AW_STRIDE 4194304ull  // N*N
#define BUCKET 128            // fixed-stride CSR bucket (deg ~ Binom(65536,1/2048), 128 = 17 sigma)

// ---------------- GEMM1 + edge scatter (independent work, one dispatch) ----------------
// blocks 0..511: h_tmp[2048,32] = X[2048,2048] @ W1[2048,32], split-K via atomics
// blocks 512..767: scatter edges into fixed-stride bucket CSR; cnt doubles as degree
__global__ __launch_bounds__(256) void k_g1scat(const float* __restrict__ X,
                                                const float* __restrict__ W1,
                                                const int* __restrict__ ei,
                                                float* __restrict__ h_tmp,
                                                int* __restrict__ cnt,
                                                int* __restrict__ csr_src) {
    __shared__ float Xs[32][33];
    __shared__ __align__(16) float Ws[32][32];
    int b = blockIdx.x;
    int t = threadIdx.x;
    if (b >= 512) {
        int e = (b - 512) * 256 + t;
        int s = ei[e], d = ei[NE + e];
        int pos = atomicAdd(&cnt[d], 1);
        if (pos < BUCKET) csr_src[d * BUCKET + pos] = s;
        return;
    }
    int rg = b >> 3, kc = b & 7;
    int r0 = rg * 32;
    int r = t >> 3, c4 = (t & 7) * 4;
    float4 acc = {0.f, 0.f, 0.f, 0.f};
    for (int kt = 0; kt < 8; ++kt) {
        int k0 = kc * 256 + kt * 32;
#pragma unroll
        for (int i = 0; i < 4; ++i) {
            int id = t + i * 256;
            int rr = id >> 5, kk = id & 31;
            Xs[rr][kk] = X[(size_t)(r0 + rr) * 2048 + k0 + kk];
            Ws[rr][kk] = W1[(size_t)(k0 + rr) * 32 + kk];
        }
        __syncthreads();
#pragma unroll
        for (int kk = 0; kk < 32; ++kk) {
            float a = Xs[r][kk];
            float4 bb = *(const float4*)&Ws[kk][c4];
            acc.x += a * bb.x; acc.y += a * bb.y; acc.z += a * bb.z; acc.w += a * bb.w;
        }
        __syncthreads();
    }
    float* dst = &h_tmp[(size_t)(r0 + r) * 32 + c4];
    atomicAdd(dst + 0, acc.x);
    atomicAdd(dst + 1, acc.y);
    atomicAdd(dst + 2, acc.z);
    atomicAdd(dst + 3, acc.w);
}

// ---------------- agg1 fused with GEMM2 epilogue ----------------
// norm recomputed per edge from cnt (== degree): rsqrtf(cnt[src]+1)*rsqrtf(cnt[n]+1)
// h1row = relu(b1 + self + sum_edges h[src]*norm) in LDS; h2t[n][:] = h1row @ W2
__global__ __launch_bounds__(256) void k_agg1(const float* __restrict__ h,
                                              const int* __restrict__ csr_src,
                                              const int* __restrict__ cnt,
                                              const float* __restrict__ b1,
                                              const float* __restrict__ W2,
                                              float* __restrict__ h2t) {
    __shared__ float W2s[H1C * H2C];  // 640
    __shared__ float red[8][32];
    __shared__ float hrow[32];
    int n = blockIdx.x;
    int t = threadIdx.x;
    for (int i = t; i < H1C * H2C; i += 256) W2s[i] = W2[i];
    int c = t & 31, s = t >> 5;  // 8 edge slices x 32 channel lanes
    int cn = cnt[n];
    float nd = rsqrtf((float)(cn + 1));
    float acc = 0.f;
    int e0 = n * BUCKET;
    for (int e = s; e < cn; e += 8) {
        int src = csr_src[e0 + e];
        float nrm = rsqrtf((float)(cnt[src] + 1)) * nd;
        acc += h[(size_t)src * 32 + c] * nrm;
    }
    red[s][c] = acc;
    __syncthreads();  // also covers W2s visibility
    if (t < 32) {
        float v = red[0][t];
#pragma unroll
        for (int i = 1; i < 8; ++i) v += red[i][t];
        v += h[(size_t)n * 32 + t] * nd * nd + b1[t];
        hrow[t] = fmaxf(v, 0.f);
    }
    __syncthreads();
    if (t < H2C) {
        float a = 0.f;
#pragma unroll
        for (int k = 0; k < H1C; ++k) a += hrow[k] * W2s[k * H2C + t];
        h2t[(size_t)n * H2C + t] = a;
    }
}

// ---------------- agg2 fused with x_actor accumulation ----------------
__global__ __launch_bounds__(256) void k_agg2(const float* __restrict__ h2t,
                                              const int* __restrict__ csr_src,
                                              const int* __restrict__ cnt,
                                              const float* __restrict__ b2,
                                              float* __restrict__ xa_slots) {
    __shared__ float red[8][32];
    int n = blockIdx.x;
    int t = threadIdx.x;
    int c = t & 31, s = t >> 5;
    int cn = cnt[n];
    float nd = rsqrtf((float)(cn + 1));
    float acc = 0.f;
    int e0 = n * BUCKET;
    if (c < H2C) {
        for (int e = s; e < cn; e += 8) {
            int src = csr_src[e0 + e];
            float nrm = rsqrtf((float)(cnt[src] + 1)) * nd;
            acc += h2t[(size_t)src * H2C + c] * nrm;
        }
    }
    red[s][c] = acc;
    __syncthreads();
    if (t < H2C) {
        float v = red[0][t];
#pragma unroll
        for (int i = 1; i < 8; ++i) v += red[i][t];
        v += h2t[(size_t)n * H2C + t] * nd * nd + b2[t];
        v = fmaxf(v, 0.f);
        atomicAdd(&xa_slots[(n & 31) * H2C + t], v);
    }
}

// ---------------- per-row logits + softmax stats + own-prefix argmax + global best ----------------
// __launch_bounds__(256,4): tell the allocator 4 waves/EU (16 waves/CU) is enough so it
// can spend ~110 VGPRs keeping all 20 aW loads in flight (round-4 counters showed 52 VGPRs
// -> ~4-deep vmcnt window -> 788 GB/s latency-bound; the w[20] batch forces 21-deep MLP).
// Per-logit FP sequence is unchanged (same k order, same += chain) -> bit-identical output.
__global__ __launch_bounds__(256, 4) void k_rows(const float* __restrict__ aW,
                                                 const float* __restrict__ ab,
                                                 const float* __restrict__ xa_slots,
                                                 float* __restrict__ rowM,
                                                 float* __restrict__ rowZ,
                                                 int* __restrict__ rowC,
                                                 float* __restrict__ rowPM,
                                                 int* __restrict__ rowPC,
                                                 unsigned long long* __restrict__ best) {
    __shared__ float xa[20];
    __shared__ float redf[256];
    __shared__ int redi[256];
    int t = threadIdx.x;
    int row = blockIdx.x;
    if (t < 20) {
        float s = 0.f;
#pragma unroll
        for (int i = 0; i < 32; ++i) s += xa_slots[i * 20 + t];
        xa[t] = s * (1.0f / 2048.0f);
    }
    __syncthreads();
    size_t base = (size_t)row * 2048;
    float l[8];
#pragma unroll
    for (int u = 0; u < 2; ++u) {
        int j0 = u * 1024 + t * 4;
        // batch all 20 plane loads first: independent addresses, 20-deep in flight
        float4 w[20];
#pragma unroll
        for (int k = 0; k < 20; ++k)
            w[k] = *(const float4*)&aW[(size_t)k * AW_STRIDE + base + j0];
        float4 acc = *(const float4*)&ab[base + j0];
#pragma unroll
        for (int k = 0; k < 20; ++k) {
            float sv = xa[k];
            acc.x += sv * w[k].x; acc.y += sv * w[k].y;
            acc.z += sv * w[k].z; acc.w += sv * w[k].w;
        }
        l[u * 4 + 0] = acc.x; l[u * 4 + 1] = acc.y;
        l[u * 4 + 2] = acc.z; l[u * 4 + 3] = acc.w;
    }
    // thread-local max/argmax (cols visited in increasing order -> strict > keeps first)
    float m = l[0];
    int mi = t * 4;
#pragma unroll
    for (int q = 1; q < 8; ++q) {
        int col = (q >> 2) * 1024 + t * 4 + (q & 3);
        if (l[q] > m) { m = l[q]; mi = col; }
    }
    redf[t] = m; redi[t] = mi;
    __syncthreads();
    for (int o = 128; o >= 1; o >>= 1) {
        if (t < o) {
            float vo = redf[t + o]; int io = redi[t + o];
            if (vo > redf[t] || (vo == redf[t] && io < redi[t])) { redf[t] = vo; redi[t] = io; }
        }
        __syncthreads();
    }
    float M = redf[0];
    int C1 = redi[0];
    __syncthreads();
    float zsum = 0.f;
#pragma unroll
    for (int q = 0; q < 8; ++q) zsum += expf(l[q] - M);
    redf[t] = zsum;
    __syncthreads();
    for (int o = 128; o >= 1; o >>= 1) {
        if (t < o) redf[t] += redf[t + o];
        __syncthreads();
    }
    float Z = redf[0];
    __syncthreads();
    // prefix (cols < C1) max/argmax over the same register-resident logits
    float pm = -INFINITY; int pj = 0x7fffffff;
#pragma unroll
    for (int q = 0; q < 8; ++q) {
        int col = (q >> 2) * 1024 + t * 4 + (q & 3);
        if (col < C1 && l[q] > pm) { pm = l[q]; pj = col; }
    }
    redf[t] = pm; redi[t] = pj;
    __syncthreads();
    for (int o = 128; o >= 1; o >>= 1) {
        if (t < o) {
            float vo = redf[t + o]; int io = redi[t + o];
            if (vo > redf[t] || (vo == redf[t] && io < redi[t])) { redf[t] = vo; redi[t] = io; }
        }
        __syncthreads();
    }
    if (t == 0) {
        rowM[row] = M; rowZ[row] = Z; rowC[row] = C1;
        rowPM[row] = redf[0]; rowPC[row] = redi[0];
        unsigned long long packed =
            ((unsigned long long)__float_as_uint(Z) << 32) | (unsigned int)row;
        atomicMax(best, ~packed);  // min Z, tie -> min row
    }
}

// ---------------- final: prefix-row scan, second action, log_probs, critic ----------------
__global__ __launch_bounds__(256) void k_final(const float* __restrict__ rowM,
                                               const float* __restrict__ rowZ,
                                               const int* __restrict__ rowC,
                                               const float* __restrict__ rowPM,
                                               const int* __restrict__ rowPC,
                                               const unsigned long long* __restrict__ best,
                                               const float* __restrict__ aW,
                                               const float* __restrict__ ab,
                                               const float* __restrict__ xa_slots,
                                               const float* __restrict__ cW,
                                               const float* __restrict__ cb,
                                               float* __restrict__ out) {
    __shared__ float xa[20];
    __shared__ float rf[256];
    __shared__ int ri[256];
    __shared__ float sM1, sZ1;
    __shared__ int sR1, sC1, sR2, sC2;
    int t = threadIdx.x;
    if (t < 20) {
        float s = 0.f;
#pragma unroll
        for (int i = 0; i < 32; ++i) s += xa_slots[i * 20 + t];
        xa[t] = s * (1.0f / 2048.0f);
    }
    if (t == 0) {
        unsigned long long bb = ~(*best);
        int r1 = (int)(unsigned int)(bb & 0xffffffffULL);
        sR1 = r1;
        sZ1 = __uint_as_float((unsigned int)(bb >> 32));
        sM1 = rowM[r1];
        sC1 = rowC[r1];
    }
    __syncthreads();
    int r1 = sR1, c1 = sC1;

    // Phase B1: best full row among rows < r1
    float z = INFINITY; int zi = 0x7fffffff;
    for (int i = t; i < r1; i += 256) {
        float v = rowZ[i];
        if (v < z || (v == z && i < zi)) { z = v; zi = i; }
    }
    rf[t] = z; ri[t] = zi;
    __syncthreads();
    for (int o = 128; o >= 1; o >>= 1) {
        if (t < o) {
            float vo = rf[t + o]; int io = ri[t + o];
            if (vo < rf[t] || (vo == rf[t] && io < ri[t])) { rf[t] = vo; ri[t] = io; }
        }
        __syncthreads();
    }
    float ZP = rf[0]; int iP = ri[0];
    __syncthreads();

    if (t == 0) {
        int r2, c2;
        if (r1 == 0 && c1 == 0) {
            r2 = 0; c2 = 0;  // argmax over all -inf -> index 0
        } else {
            bool hasA = (r1 > 0), hasB = (c1 > 0);
            float pA = hasA ? 1.0f / ZP : -INFINITY;
            // Phase B2 precomputed in k_rows from the same register-resident logits
            float pB = hasB ? expf(rowPM[r1] - sM1) / sZ1 : -INFINITY;
            if (hasB && (!hasA || pB > pA)) { r2 = r1; c2 = rowPC[r1]; }
            else                            { r2 = iP; c2 = rowC[iP]; }
        }
        sR2 = r2; sC2 = c2;
        out[0] = (float)r1; out[1] = (float)c1;
        out[2] = (float)r2; out[3] = (float)c2;
        float cr = 0.f;
#pragma unroll
        for (int k = 0; k < 20; ++k) cr += xa[k] * cW[k];
        out[8] = cr + cb[0];
    }
    __syncthreads();

    // Phase C: log_probs index the FLATTENED probs at {r1,c1,r2,c2} => row 0 of probs
    if (t < 4) {
        int a = (t == 0) ? sR1 : (t == 1) ? sC1 : (t == 2) ? sR2 : sC2;
        float acc = ab[a];
#pragma unroll
        for (int k = 0; k < 20; ++k) acc += xa[k] * aW[(size_t)k * AW_STRIDE + a];
        float lp = (acc - rowM[0]) - logf(rowZ[0]);
        out[4 + t] = -lp;
    }
}

extern "C" void kernel_launch(void* const* d_in, const int* in_sizes, int n_in,
                              void* d_out, int out_size, void* d_ws, size_t ws_size,
                              hipStream_t stream) {
    const float* x  = (const float*)d_in[0];
    const int*   ei = (const int*)d_in[1];
    const float* W1 = (const float*)d_in[2];
    const float* b1 = (const float*)d_in[3];
    const float* W2 = (const float*)d_in[4];
    const float* b2 = (const float*)d_in[5];
    const float* aW = (const float*)d_in[6];
    const float* ab = (const float*)d_in[7];
    const float* cW = (const float*)d_in[8];
    const float* cb = (const float*)d_in[9];
    float* out = (float*)d_out;

    char* p = (char*)d_ws;
    auto alloc = [&](size_t bytes) {
        void* r = (void*)p;
        p += (bytes + 255) & ~(size_t)255;
        return r;
    };
    // zero region (one memset): cnt, xa_slots, h_tmp, best
    int*   cnt      = (int*)alloc(2048 * 4);
    float* xa_slots = (float*)alloc(640 * 4);
    float* h_tmp    = (float*)alloc(65536 * 4);
    unsigned long long* best = (unsigned long long*)alloc(8);
    size_t zero_bytes = (size_t)(p - (char*)d_ws);
    int*   csr_src  = (int*)alloc(2048 * BUCKET * 4);
    float* h2t      = (float*)alloc(40960 * 4);
    float* rowM     = (float*)alloc(2048 * 4);
    float* rowZ     = (float*)alloc(2048 * 4);
    int*   rowC     = (int*)alloc(2048 * 4);
    float* rowPM    = (float*)alloc(2048 * 4);
    int*   rowPC    = (int*)alloc(2048 * 4);

    hipMemsetAsync(d_ws, 0, zero_bytes, stream);
    k_g1scat<<<768, 256, 0, stream>>>(x, W1, ei, h_tmp, cnt, csr_src);
    k_agg1<<<2048, 256, 0, stream>>>(h_tmp, csr_src, cnt, b1, W2, h2t);
    k_agg2<<<2048, 256, 0, stream>>>(h2t, csr_src, cnt, b2, xa_slots);
    k_rows<<<2048, 256, 0, stream>>>(aW, ab, xa_slots, rowM, rowZ, rowC, rowPM, rowPC, best);
    k_final<<<1, 256, 0, stream>>>(rowM, rowZ, rowC, rowPM, rowPC, best, aW, ab, xa_slots, cW, cb, out);
}